// Round 5
// baseline (570.842 us; speedup 1.0000x reference)
//
#include <hip/hip_runtime.h>
#include <cstdint>
#include <cstddef>

// LSTM cell: g = [X|Hprev] @ [Wih|Whh]^T + b -> gates -> (h_new, c_new)
// Round 8: faithful m201 8-phase port. Pass 1 (fp32->fp16 into d_ws) unchanged.
// Pass 2 v7: 256x256 tile, BK=64, 8 waves (2Mx4N), P/Q double-buffered LDS
// (A: 2x32KB, B: 2x32KB = 128KB), 8 phases per iter covering 2 K-tiles:
//   phase = {quadrant frag ds_reads (A-frags REUSED on nq=1 phases: 4-or-12
//   reads) + ONE half-tile stage (2 x gld16) -> s_barrier -> lgkmcnt(0) ->
//   setprio(1) -> 16 MFMA -> setprio(0) -> [vmcnt(2) at ph4/ph8] -> s_barrier}
// Stage ledger (h staged >=1 barrier after last read; read >=1 vmcnt+barrier
// after stage): ph1 QA.h1[2j+1], ph2 QB.h0, ph3 QB.h1, ph4 PA.h0[2j+2]+vm,
// ph5 PA.h1, ph6 PB.h0, ph7 PB.h1, ph8 QA.h0[2j+3]+vm.
// No sched_barrier pins (m141). XOR chunk swizzle on 128B rows (8 chunks,
// cg = cl ^ (row&7)), both-sides (pre-swizzled global src, swizzled ds_read).
// Kept: hblk-fast XCD mapping (r3: FETCH 573->328MB), gate-interleaved B,
// register-only epilogue.

typedef _Float16 half8 __attribute__((ext_vector_type(8)));
typedef float f32x4 __attribute__((ext_vector_type(4)));

__device__ __forceinline__ float sigmoidf_(float x) { return 1.0f / (1.0f + __expf(-x)); }
__device__ __forceinline__ float tanh_fast(float x) { return 2.0f / (1.0f + __expf(-2.0f * x)) - 1.0f; }

__device__ __forceinline__ void gld16(const void* g, void* lds) {
    // 16B/lane async global->LDS; lds base must be wave-uniform (dest = base + lane*16)
    __builtin_amdgcn_global_load_lds((const __attribute__((address_space(1))) uint32_t*)g,
                                     (__attribute__((address_space(3))) uint32_t*)lds, 16, 0, 0);
}

// ---------------- pass 1: fp32 -> fp16 ----------------
__global__ __launch_bounds__(256)
void convert_to_f16(const float* __restrict__ X, const float* __restrict__ H,
                    const float* __restrict__ Wih, const float* __restrict__ Whh,
                    _Float16* __restrict__ ws, long nX, long nW)
{
    long e = ((long)blockIdx.x * 256 + threadIdx.x) * 8;
    long total = 2 * nX + 2 * nW;
    if (e >= total) return;
    const float* src; long off;
    if (e < nX)              { src = X;   off = e; }
    else if (e < 2 * nX)     { src = H;   off = e - nX; }
    else if (e < 2 * nX + nW){ src = Wih; off = e - 2 * nX; }
    else                     { src = Whh; off = e - 2 * nX - nW; }
    float4 a = *(const float4*)(src + off);
    float4 b = *(const float4*)(src + off + 4);
    half8 h;
    h[0]=(_Float16)a.x; h[1]=(_Float16)a.y; h[2]=(_Float16)a.z; h[3]=(_Float16)a.w;
    h[4]=(_Float16)b.x; h[5]=(_Float16)b.y; h[6]=(_Float16)b.z; h[7]=(_Float16)b.w;
    *(half8*)(ws + e) = h;
}

// ---------------- pass 2: 256x256 BK=64 8-phase MFMA GEMM + fused gates ----------------
__global__ __launch_bounds__(512, 2)
void lstm_mfma_v7(const _Float16* __restrict__ ws,   // Xh | Hh | Wih_h | Whh_h
                  const float* __restrict__ Cprev,
                  const float* __restrict__ bih, const float* __restrict__ bhh,
                  float* __restrict__ Out, int Btot, int mblocks)
{
    // A: P@0, Q@32768; B: P@65536, Q@98304. Each tile buffer [256 rows][128B].
    __shared__ alignas(16) char smem[131072];

    const long nX = (long)Btot * 1024;
    const long nW = 4096L * 1024;
    const _Float16* Xh = ws;
    const _Float16* Hh = ws + nX;
    const _Float16* Wi = ws + 2 * nX;
    const _Float16* Wh = ws + 2 * nX + nW;

    const int tid = threadIdx.x;
    const int w = tid >> 6, l = tid & 63;
    const int lr = l & 15, q = l >> 4;
    const int wm = w >> 2, wn = w & 3;                // wave grid: 2 (M) x 4 (N)

    // XCD-aware chunked swizzle (bijective: nwg = 1024, % 8 == 0)
    const int nwg = gridDim.x;
    int bx = blockIdx.x;
    if ((nwg & 7) == 0) bx = (bx & 7) * (nwg >> 3) + (bx >> 3);
    // hblk-FAST mapping: co-resident blocks on an XCD share A-panels (L2 reuse)
    const int hblk = (bx & 15) * 64;
    const int m0   = (bx >> 4) * 256;

    // ---- staging precompute. Half-tile (128 rows x 128B = 16KB) staged by two
    //      gld16 calls j=0,1; call j, wave w, lane l covers LDS byte
    //      off = j*8192 + w*1024 + l*16 within the half. Linear LDS dest;
    //      global source pre-swizzled: chunk cl holds global k-chunk cl^(row&7).
    uint32_t gA0[2], gB0[2];
    #pragma unroll
    for (int j = 0; j < 2; ++j) {
        uint32_t off = (uint32_t)(j * 8192 + w * 1024 + l * 16);
        uint32_t lr_ = off >> 7;                       // row within half: 0..127
        uint32_t cl  = (off >> 4) & 7u;
        uint32_t cg  = cl ^ (lr_ & 7u);
        gA0[j] = (uint32_t)(m0 + (int)lr_) * 1024u + cg * 8u;          // + h*131072 + (ts&15)*64
        uint32_t g_  = (lr_ >> 4) & 3u;                // gate-interleaved B rows
        uint32_t hs  = (lr_ >> 6) * 16u + (lr_ & 15u);
        gB0[j] = (g_ * 1024u + (uint32_t)hblk + hs) * 1024u + cg * 8u; // + h*32768 + (ts&15)*64
    }
    const uint32_t ub0 = (uint32_t)(w * 1024);         // wave-uniform LDS base, call 0
    const uint32_t ub1 = (uint32_t)(8192 + w * 1024);  // call 1

    // ---- fragment-read pointers (swizzled chunk; ks in {0,1} selects 64B k-half) ----
    const uint32_t ckA0 = (uint32_t)(((0 * 4 + q) ^ (lr & 7)) * 16);
    const uint32_t ckA1 = (uint32_t)(((1 * 4 + q) ^ (lr & 7)) * 16);
    const char* pA0 = smem + (uint32_t)((wm * 128 + lr) * 128) + ckA0;  // + buf*32768 + mq*8192 + mt*2048
    const char* pA1 = smem + (uint32_t)((wm * 128 + lr) * 128) + ckA1;
    const char* pB0 = smem + 65536u + (uint32_t)((wn * 64 + lr) * 128) + ckA0;  // + buf*32768 + g*2048
    const char* pB1 = smem + 65536u + (uint32_t)((wn * 64 + lr) * 128) + ckA1;

    f32x4 acc[8][4];
    #pragma unroll
    for (int i = 0; i < 8; ++i)
        #pragma unroll
        for (int jj = 0; jj < 4; ++jj)
            acc[i][jj] = (f32x4){0.f, 0.f, 0.f, 0.f};

    // stage one half-tile: which 0=A 1=B, bufsel 0=P 1=Q, h 0/1, ts = K-tile 0..31
    auto stage = [&](int which, int bufsel, int h, int ts) {
        const _Float16* src;
        uint32_t g0, g1;
        if (which == 0) { src = (ts < 16) ? Xh : Hh; g0 = gA0[0] + (uint32_t)h * 131072u; g1 = gA0[1] + (uint32_t)h * 131072u; }
        else            { src = (ts < 16) ? Wi : Wh; g0 = gB0[0] + (uint32_t)h * 32768u;  g1 = gB0[1] + (uint32_t)h * 32768u;  }
        const uint32_t kof = (uint32_t)(ts & 15) * 64u;
        char* base = smem + (which ? 65536 : 0) + bufsel * 32768 + h * 16384;
        gld16(src + g0 + kof, base + ub0);
        gld16(src + g1 + kof, base + ub1);
    };

    half8 af[4][2], bf[2][2];

    // ---- prologue: P <- tile 0 (4 halves), QA.h0 <- tile 1; publish P ----
    stage(0, 0, 0, 0); stage(0, 0, 1, 0);
    stage(1, 0, 0, 0); stage(1, 0, 1, 0);
    stage(0, 1, 0, 1);
    asm volatile("s_waitcnt vmcnt(2)" ::: "memory");   // P's 4 halves landed
    __builtin_amdgcn_s_barrier();

    // One phase: quadrant (MQ,NQ) of buffer BUFSEL; READA reloads A-frags.
#define PH(BUFSEL, MQ, NQ, READA, SW, SB, SH, ST, DOVM)                              \
    {                                                                                \
        if (READA) {                                                                 \
            _Pragma("unroll")                                                        \
            for (int mt = 0; mt < 4; ++mt) {                                         \
                af[mt][0] = *(const half8*)(pA0 + (BUFSEL) * 32768 + (MQ) * 8192 + mt * 2048); \
                af[mt][1] = *(const half8*)(pA1 + (BUFSEL) * 32768 + (MQ) * 8192 + mt * 2048); \
            }                                                                        \
        }                                                                            \
        _Pragma("unroll")                                                            \
        for (int gl = 0; gl < 2; ++gl) {                                             \
            bf[gl][0] = *(const half8*)(pB0 + (BUFSEL) * 32768 + ((NQ) * 2 + gl) * 2048); \
            bf[gl][1] = *(const half8*)(pB1 + (BUFSEL) * 32768 + ((NQ) * 2 + gl) * 2048); \
        }                                                                            \
        stage((SW), (SB), (SH), (ST));                                               \
        __builtin_amdgcn_s_barrier();                                                \
        asm volatile("s_waitcnt lgkmcnt(0)" ::: "memory");                           \
        __builtin_amdgcn_s_setprio(1);                                               \
        _Pragma("unroll")                                                            \
        for (int mt = 0; mt < 4; ++mt)                                               \
            _Pragma("unroll")                                                        \
            for (int gl = 0; gl < 2; ++gl) {                                         \
                acc[(MQ)*4+mt][(NQ)*2+gl] = __builtin_amdgcn_mfma_f32_16x16x32_f16(af[mt][0], bf[gl][0], acc[(MQ)*4+mt][(NQ)*2+gl], 0, 0, 0); \
                acc[(MQ)*4+mt][(NQ)*2+gl] = __builtin_amdgcn_mfma_f32_16x16x32_f16(af[mt][1], bf[gl][1], acc[(MQ)*4+mt][(NQ)*2+gl], 0, 0, 0); \
            }                                                                        \
        __builtin_amdgcn_s_setprio(0);                                               \
        if (DOVM) asm volatile("s_waitcnt vmcnt(2)" ::: "memory");                   \
        __builtin_amdgcn_s_barrier();                                                \
    }

    #pragma unroll 1
    for (int j = 0; j < 16; ++j) {
        const int t1 = 2 * j + 1;                              // T1 (Q), this iter
        const int tp = (2 * j + 2 > 31) ? 31 : 2 * j + 2;      // P's next
        const int tq = (2 * j + 3 > 31) ? 31 : 2 * j + 3;      // Q's next
        PH(0, 0, 0, 1, 0, 1, 1, t1, 0)   // ph1: T0 (mq0,nq0)  | stage QA.h1[t1]
        PH(0, 0, 1, 0, 1, 1, 0, t1, 0)   // ph2: T0 (mq0,nq1)  | stage QB.h0[t1]
        PH(0, 1, 0, 1, 1, 1, 1, t1, 0)   // ph3: T0 (mq1,nq0)  | stage QB.h1[t1]
        PH(0, 1, 1, 0, 0, 0, 0, tp, 1)   // ph4: T0 (mq1,nq1)  | stage PA.h0[tp] +vmcnt(2)
        PH(1, 0, 0, 1, 0, 0, 1, tp, 0)   // ph5: T1 (mq0,nq0)  | stage PA.h1[tp]
        PH(1, 0, 1, 0, 1, 0, 0, tp, 0)   // ph6: T1 (mq0,nq1)  | stage PB.h0[tp]
        PH(1, 1, 0, 1, 1, 0, 1, tp, 0)   // ph7: T1 (mq1,nq0)  | stage PB.h1[tp]
        PH(1, 1, 1, 0, 0, 1, 0, tq, 1)   // ph8: T1 (mq1,nq1)  | stage QA.h0[tq] +vmcnt(2)
    }
#undef PH
    asm volatile("s_waitcnt vmcnt(0)" ::: "memory");   // drain tail stages

    // ---- epilogue: register-only. acc[mf][g][r]: m = m0+wm*128+mf*16+q*4+r,
    //      gate g, h = hblk + wn*16 + lr  (all 4 gates in-thread) ----
    const int h = hblk + wn * 16 + lr;
    float bs[4];
    #pragma unroll
    for (int g = 0; g < 4; ++g) bs[g] = bih[g * 1024 + h] + bhh[g * 1024 + h];
    const long c_off = (long)Btot * 1024;
    const int mbase = m0 + wm * 128 + q * 4;

    #pragma unroll
    for (int mf = 0; mf < 8; ++mf) {
        #pragma unroll
        for (int r = 0; r < 4; ++r) {
            const int m = mbase + mf * 16 + r;
            const long idx = (long)m * 1024 + h;
            float gi = acc[mf][0][r] + bs[0];
            float gf = acc[mf][1][r] + bs[1];
            float gc = acc[mf][2][r] + bs[2];
            float go = acc[mf][3][r] + bs[3];
            float ig = sigmoidf_(gi), fg = sigmoidf_(gf);
            float cd = tanh_fast(gc), og = sigmoidf_(go);
            float c_new = Cprev[idx] * fg + ig * cd;
            Out[idx]         = tanh_fast(c_new) * og;
            Out[c_off + idx] = c_new;
        }
    }
}

// ---------------- fallback (round-2 kernel): used only if ws too small ----------------
__global__ __launch_bounds__(256, 2)
void lstm_mfma_f16_fb(const float* __restrict__ X, const float* __restrict__ Hprev,
                      const float* __restrict__ Cprev,
                      const float* __restrict__ Wih, const float* __restrict__ Whh,
                      const float* __restrict__ bih, const float* __restrict__ bhh,
                      float* __restrict__ Out, int Btot, int mblocks)
{
    __shared__ alignas(16) _Float16 As[128][40];
    __shared__ alignas(16) _Float16 Bs[256][40];
    const int tid = threadIdx.x;
    const int w = tid >> 6, lane = tid & 63, lr = lane & 15, q = lane >> 4;
    const int bx = blockIdx.x, mblk = bx % mblocks, nblk = bx / mblocks;
    const int m0 = mblk * 128, hblk = nblk * 64;
    const int sr = tid >> 1, sc = tid & 1;
    f32x4 acc[8][4];
    #pragma unroll
    for (int mt = 0; mt < 8; ++mt)
        #pragma unroll
        for (int g = 0; g < 4; ++g) acc[mt][g] = (f32x4){0.f,0.f,0.f,0.f};
    float4 pa[4], pb0[4], pb1[4];
    const int rb1 = sr + 128;
    const size_t wrow0 = (size_t)((sr >> 6) * 1024 + hblk + (sr & 63)) * 1024;
    const size_t wrow1 = (size_t)((rb1 >> 6) * 1024 + hblk + (rb1 & 63)) * 1024;
    const size_t arow  = (size_t)(m0 + sr) * 1024;
    auto stage_load = [&](int tile) {
        const int phase = tile >> 5;
        const int k0 = (tile & 31) * 32 + sc * 16;
        const float* Ap = phase ? Hprev : X;
        const float* Wp = phase ? Whh : Wih;
        const float4* ap = (const float4*)(Ap + arow + k0);
        const float4* b0 = (const float4*)(Wp + wrow0 + k0);
        const float4* b1 = (const float4*)(Wp + wrow1 + k0);
        #pragma unroll
        for (int i = 0; i < 4; ++i) { pa[i] = ap[i]; pb0[i] = b0[i]; pb1[i] = b1[i]; }
    };
    auto pack8 = [](float4 a, float4 b) {
        half8 h;
        h[0]=(_Float16)a.x; h[1]=(_Float16)a.y; h[2]=(_Float16)a.z; h[3]=(_Float16)a.w;
        h[4]=(_Float16)b.x; h[5]=(_Float16)b.y; h[6]=(_Float16)b.z; h[7]=(_Float16)b.w;
        return h;
    };
    stage_load(0);
    for (int tile = 0; tile < 64; ++tile) {
        __syncthreads();
        *(half8*)&As[sr][sc*16]        = pack8(pa[0], pa[1]);
        *(half8*)&As[sr][sc*16+8]      = pack8(pa[2], pa[3]);
        *(half8*)&Bs[sr][sc*16]        = pack8(pb0[0], pb0[1]);
        *(half8*)&Bs[sr][sc*16+8]      = pack8(pb0[2], pb0[3]);
        *(half8*)&Bs[sr+128][sc*16]    = pack8(pb1[0], pb1[1]);
        *(half8*)&Bs[sr+128][sc*16+8]  = pack8(pb1[2], pb1[3]);
        __syncthreads();
        if (tile + 1 < 64) stage_load(tile + 1);
        half8 bf[4];
        #pragma unroll
        for (int g = 0; g < 4; ++g) bf[g] = *(const half8*)&Bs[g*64 + w*16 + lr][q*8];
        #pragma unroll
        for (int mt = 0; mt < 8; ++mt) {
            half8 a = *(const half8*)&As[mt*16 + lr][q*8];
            #pragma unroll
            for (int g = 0; g < 4; ++g)
                acc[mt][g] = __builtin_amdgcn_mfma_f32_16x16x32_f16(a, bf[g], acc[mt][g], 0, 0, 0);
        }
    }
    const int h = hblk + w * 16 + lr;
    float bs0 = bih[h] + bhh[h];
    float bs1 = bih[1024+h] + bhh[1024+h];
    float bs2 = bih[2048+h] + bhh[2048+h];
    float bs3 = bih[3072+h] + bhh[3072+h];
    const size_t c_off = (size_t)Btot * 1024;
    #pragma unroll
    for (int mt = 0; mt < 8; ++mt)
        #pragma unroll
        for (int r = 0; r < 4; ++r) {
            const int m = m0 + mt*16 + q*4 + r;
            const size_t idx = (size_t)m * 1024 + h;
            float gi = acc[mt][0][r]+bs0, gf = acc[mt][1][r]+bs1;
            float gc = acc[mt][2][r]+bs2, go = acc[mt][3][r]+bs3;
            float ig = sigmoidf_(gi), fg = sigmoidf_(gf);
            float cd = tanh_fast(gc), og = sigmoidf_(go);
            float c_new = Cprev[idx]*fg + ig*cd;
            Out[idx] = tanh_fast(c_new)*og;
            Out[c_off+idx] = c_new;
        }
}

extern "C" void kernel_launch(void* const* d_in, const int* in_sizes, int n_in,
                              void* d_out, int out_size, void* d_ws, size_t ws_size,
                              hipStream_t stream) {
    const float* X     = (const float*)d_in[0];
    const float* Hprev = (const float*)d_in[1];
    const float* Cprev = (const float*)d_in[2];
    const float* Wih   = (const float*)d_in[3];
    const float* Whh   = (const float*)d_in[4];
    const float* bih   = (const float*)d_in[5];
    const float* bhh   = (const float*)d_in[6];
    float* Out = (float*)d_out;

    const int Btot = in_sizes[0] / 1024;
    const long nX = (long)Btot * 1024, nW = 4096L * 1024;
    const size_t need = (size_t)(2 * nX + 2 * nW) * sizeof(_Float16);

    if (ws_size >= need && (Btot % 256) == 0) {
        _Float16* ws = (_Float16*)d_ws;
        const long total = 2 * nX + 2 * nW;
        const int cblocks = (int)((total / 8 + 255) / 256);
        hipLaunchKernelGGL(convert_to_f16, dim3(cblocks), dim3(256), 0, stream,
                           X, Hprev, Wih, Whh, ws, nX, nW);
        const int mblocks = Btot / 256;               // 64
        const int nblocks = 1024 / 64;                // 16
        hipLaunchKernelGGL(lstm_mfma_v7, dim3(mblocks * nblocks), dim3(512), 0, stream,
                           ws, Cprev, bih, bhh, Out, Btot, mblocks);
    } else {
        const int mblocks = Btot / 128;
        hipLaunchKernelGGL(lstm_mfma_f16_fb, dim3(mblocks * 16), dim3(256), 0, stream,
                           X, Hprev, Cprev, Wih, Whh, bih, bhh, Out, Btot, mblocks);
    }
}